// Round 10
// baseline (197.072 us; speedup 1.0000x reference)
//
#include <hip/hip_runtime.h>
#include <hip/hip_bf16.h>

#define D_MODEL 96
#define D_INNER 192
#define BATCH 32
#define HH 56
#define WW 56
#define NPIX (BATCH*HH*WW)   // 100352
#define LN_EPS 1e-5f
#define TAPS 18432           // shorts per tap slab (96 oc * 192 ic)
#define TAPBYTES 36864
#define K2_NWG 784           // NPIX / 128
#define K2_CPX 98            // blocks per XCD chunk (784 = 8 * 98, bijective)

typedef unsigned short ushort_t;
typedef __attribute__((ext_vector_type(8))) short short8;   // 8 bf16 (4 VGPRs)
typedef __attribute__((ext_vector_type(4))) float f32x4;

// conv weights transposed to [tap][oc][ic] bf16 (331 KB) and
// in_proj live-half transposed to [oc=192][ic=96] bf16 (36.9 KB), module .data.
__device__ __align__(16) ushort_t g_Wt[9 * 96 * 192];
__device__ __align__(16) ushort_t g_Wit[192 * 96];

// round-to-nearest-even f32 -> bf16
static __device__ __forceinline__ unsigned short f2bf(float f) {
    unsigned u = __float_as_uint(f);
    unsigned r = (u + 0x7fffu + ((u >> 16) & 1u)) >> 16;
    return (unsigned short)r;
}

// ---------------------------------------------------------------------------
// Kernel 0: weight prep. (unchanged, verified)
// ---------------------------------------------------------------------------
__global__ __launch_bounds__(256) void k0_wt(const float* __restrict__ Wc,
                                             const float* __restrict__ Wi) {
    const int o = blockIdx.x * 256 + threadIdx.x;
    if (o < 9 * 96 * 192) {
        const int tap = o / (96 * 192);
        const int rem = o - tap * 96 * 192;
        const int oc = rem / 192;
        const int ic = rem - oc * 192;
        g_Wt[o] = f2bf(Wc[(tap * 192 + ic) * 96 + oc]);
    }
    if (o < 192 * 96) {
        const int oc = o / 96, ic = o - oc * 96;
        g_Wit[o] = f2bf(Wi[ic * 384 + oc]);
    }
}

// ---------------------------------------------------------------------------
// Kernel 1: LayerNorm + in_projection (96 -> live 192) via bf16 MFMA.
// (byte-identical to round 9, verified passing)
// ---------------------------------------------------------------------------
__global__ __launch_bounds__(256) void k1_ln_proj(
    const float* __restrict__ X, const float* __restrict__ ln_w,
    const float* __restrict__ ln_b, const float* __restrict__ b_in,
    ushort_t* __restrict__ X1)
{
    __shared__ ushort_t sH[64 * 104];    // 13,312 B (GEMM B-operand)
    __shared__ ushort_t sO[64 * 200];    // 25,600 B (output transpose)
    const int t = threadIdx.x;

    const int g = t >> 2, tig = t & 3;
    const int pix = blockIdx.x * 64 + g;
    const float* xp = X + (size_t)pix * 96 + tig * 24;
    float4 xq[6];
    float s = 0.f;
    #pragma unroll
    for (int c = 0; c < 6; ++c) {
        xq[c] = *(const float4*)(xp + c * 4);
        s += xq[c].x + xq[c].y + xq[c].z + xq[c].w;
    }
    s += __shfl_xor(s, 1, 4);
    s += __shfl_xor(s, 2, 4);
    const float mu = s * (1.f / 96.f);
    float v = 0.f;
    #pragma unroll
    for (int c = 0; c < 6; ++c) {
        const float d0 = xq[c].x - mu, d1 = xq[c].y - mu;
        const float d2 = xq[c].z - mu, d3 = xq[c].w - mu;
        v += d0 * d0 + d1 * d1 + d2 * d2 + d3 * d3;
    }
    v += __shfl_xor(v, 1, 4);
    v += __shfl_xor(v, 2, 4);
    const float rs = rsqrtf(v * (1.f / 96.f) + LN_EPS);
    #pragma unroll
    for (int c = 0; c < 6; ++c) {
        const float4 lw = *(const float4*)(ln_w + tig * 24 + c * 4);
        const float4 lb = *(const float4*)(ln_b + tig * 24 + c * 4);
        const unsigned p0 = (unsigned)f2bf((xq[c].x - mu) * rs * lw.x + lb.x)
                          | ((unsigned)f2bf((xq[c].y - mu) * rs * lw.y + lb.y) << 16);
        const unsigned p1 = (unsigned)f2bf((xq[c].z - mu) * rs * lw.z + lb.z)
                          | ((unsigned)f2bf((xq[c].w - mu) * rs * lw.w + lb.w) << 16);
        uint2 u; u.x = p0; u.y = p1;
        *(uint2*)&sH[g * 104 + tig * 24 + c * 4] = u;
    }
    __syncthreads();

    const int w = t >> 6, l = t & 63;
    const int lm = l & 15, lq = l >> 4;
    const ushort_t* hp = &sH[(w * 16 + lm) * 104 + lq * 8];

    f32x4 acc[12];
    const f32x4 zf = {0.f, 0.f, 0.f, 0.f};
    #pragma unroll
    for (int mt = 0; mt < 12; ++mt) acc[mt] = zf;

    #pragma unroll
    for (int kk = 0; kk < 3; ++kk) {
        const short8 hb = *(const short8*)(hp + kk * 32);
        #pragma unroll
        for (int mt = 0; mt < 12; ++mt) {
            const short8 wa = *(const short8*)(g_Wit + (mt * 16 + lm) * 96 + kk * 32 + lq * 8);
            acc[mt] = __builtin_amdgcn_mfma_f32_16x16x32_bf16(wa, hb, acc[mt], 0, 0, 0);
        }
    }

    #pragma unroll
    for (int mt = 0; mt < 12; ++mt) {
        const int oc0 = mt * 16 + lq * 4;
        const float4 bv = *(const float4*)(b_in + oc0);
        uint2 u;
        u.x = (unsigned)f2bf(acc[mt][0] + bv.x) | ((unsigned)f2bf(acc[mt][1] + bv.y) << 16);
        u.y = (unsigned)f2bf(acc[mt][2] + bv.z) | ((unsigned)f2bf(acc[mt][3] + bv.w) << 16);
        *(uint2*)&sO[(w * 16 + lm) * 200 + oc0] = u;
    }
    __syncthreads();

    const char* sOb = (const char*)sO + w * 16 * 400;
    char* gdst = (char*)X1 + (size_t)(blockIdx.x * 64 + w * 16) * 384;
    #pragma unroll
    for (int c = 0; c < 6; ++c) {
        const int gb = c * 1024 + l * 16;
        const int px = gb / 384, b = gb - px * 384;
        const uint4 val = *(const uint4*)(sOb + px * 400 + b);
        *(uint4*)(gdst + gb) = val;
    }
}

// ---------------------------------------------------------------------------
// Kernel 2: 3x3 conv (192 -> 96) MFMA + bias + SiLU + residual.
// Round-10 restructure for OCCUPANCY (round 9: 1.53 blocks/CU, 14% occ,
// MfmaUtil 11%): 128 px/block (4 waves x 32 px), SINGLE-buffered tap slab
// (36,864 B LDS -> 4 blocks/CU), grid 784 = fully co-resident. Weight
// staging keeps the verified reg-prefetch (issue tap+1 loads before tap's
// MFMA) + same XOR involution; 2 barriers/tap hidden by 3-4 resident
// blocks. T1 XCD swizzle (784 = 8*98): an image's 25 blocks run on one
// XCD so its 1.2 MB X1 stays in that L2 across the 9x halo re-reads.
// ---------------------------------------------------------------------------
__global__ __launch_bounds__(256, 4) void k2_conv_mfma(
    const ushort_t* __restrict__ X1, const float* __restrict__ conv_b,
    const float* __restrict__ X, float* __restrict__ OUT)
{
    __shared__ ushort_t sW[TAPS];   // 36,864 B single buffer
    const int t = threadIdx.x;
    const int w = t >> 6, l = t & 63;
    const int lm = l & 15, lq = l >> 4;

    // XCD-aware bijective swizzle: XCD (bid&7) processes logical blocks
    // [ (bid&7)*98, +98 ) -> consecutive image regions per XCD.
    const int lb = ((int)blockIdx.x & 7) * K2_CPX + ((int)blockIdx.x >> 3);

    // wave's 32-px span; 32 | 3136 so it never crosses an image
    const int Pw = lb * 128 + w * 32;
    const int img = Pw / 3136;
    const int pw0 = Pw - img * 3136;
    int rr[2], cc[2];
    #pragma unroll
    for (int i = 0; i < 2; ++i) {
        const int pl = pw0 + i * 16 + lm;
        rr[i] = pl / 56;
        cc[i] = pl - rr[i] * 56;
    }
    const size_t imgbase = (size_t)img * 3136 * 192;

    f32x4 acc[2][6];
    const f32x4 zf = {0.f, 0.f, 0.f, 0.f};
    #pragma unroll
    for (int i = 0; i < 2; ++i)
        #pragma unroll
        for (int n = 0; n < 6; ++n) acc[i][n] = zf;

    const short8 zero8 = {0, 0, 0, 0, 0, 0, 0, 0};
    const int bkey = (lm & 7) << 4;
    const int bbase0 = lm * 384 + lq * 16;   // logical byte offset in tap slab

    // staging geometry: thread t owns 9 x 16-B chunks at D = j*4096 + t*16
    const int sbase = t * 16;

    // ---- prologue: stage tap 0 ----
    uint4 r[9];
    #pragma unroll
    for (int j = 0; j < 9; ++j)
        r[j] = *(const uint4*)((const char*)g_Wt + sbase + j * 4096);
    #pragma unroll
    for (int j = 0; j < 9; ++j) {
        const int D = sbase + j * 4096;
        *(uint4*)((char*)sW + (D ^ (((D / 384) & 7) << 4))) = r[j];
    }
    __syncthreads();

    #pragma unroll 1
    for (int tap = 0; tap < 9; ++tap) {
        // issue next tap's global loads early (hidden under this tap's MFMA)
        if (tap < 8) {
            const char* gsrc = (const char*)g_Wt + (size_t)(tap + 1) * TAPBYTES;
            #pragma unroll
            for (int j = 0; j < 9; ++j)
                r[j] = *(const uint4*)(gsrc + sbase + j * 4096);
        }

        const int ky = tap / 3, kx = tap - (tap / 3) * 3;
        const ushort_t* abase[2];
        bool av[2];
        #pragma unroll
        for (int i = 0; i < 2; ++i) {
            const int gr = rr[i] + ky - 1, gc = cc[i] + kx - 1;
            av[i] = (gr >= 0) && (gr < HH) && (gc >= 0) && (gc < WW);
            abase[i] = X1 + imgbase + (size_t)(gr * WW + gc) * 192 + lq * 8;
        }

        #pragma unroll
        for (int kk = 0; kk < 6; ++kk) {
            short8 b[6];
            #pragma unroll
            for (int n = 0; n < 6; ++n) {
                const int A = bbase0 + n * 6144 + kk * 64;   // n*16*384 B
                b[n] = *(const short8*)((const char*)sW + (A ^ bkey));
            }
            short8 a[2];
            #pragma unroll
            for (int i = 0; i < 2; ++i)
                a[i] = av[i] ? *(const short8*)(abase[i] + kk * 32) : zero8;
            #pragma unroll
            for (int i = 0; i < 2; ++i)
                #pragma unroll
                for (int n = 0; n < 6; ++n)
                    acc[i][n] = __builtin_amdgcn_mfma_f32_16x16x32_bf16(
                        a[i], b[n], acc[i][n], 0, 0, 0);
        }
        __syncthreads();            // all waves done reading sW

        if (tap < 8) {
            #pragma unroll
            for (int j = 0; j < 9; ++j) {
                const int D = sbase + j * 4096;
                *(uint4*)((char*)sW + (D ^ (((D / 384) & 7) << 4))) = r[j];
            }
            __syncthreads();        // sW ready for next tap
        }
    }

    // ---- coalesced epilogue through LDS (sW now dead) ----
    float* sY = (float*)sW + w * 1600;   // 16 px * 100 dwords per wave
    float bvn[6];
    #pragma unroll
    for (int n = 0; n < 6; ++n) bvn[n] = conv_b[n * 16 + lm];

    #pragma unroll
    for (int i = 0; i < 2; ++i) {        // fully unrolled: acc stays in VGPRs
        #pragma unroll
        for (int n = 0; n < 6; ++n) {
            #pragma unroll
            for (int r4 = 0; r4 < 4; ++r4) {
                const float y = acc[i][n][r4] + bvn[n];
                const float sig = 1.f / (1.f + __expf(-y));
                sY[(lq * 4 + r4) * 100 + n * 16 + lm] = y * sig;
            }
        }
        __syncthreads();
        const float* gx = X + (size_t)(Pw + i * 16) * 96;
        float* go = OUT + (size_t)(Pw + i * 16) * 96;
        #pragma unroll
        for (int c = 0; c < 6; ++c) {
            const int d = c * 256 + l * 4;           // dword index in 6144-B span
            const int px = d / 96, b = d - px * 96;
            const f32x4 yv = *(const f32x4*)(sY + px * 100 + b);
            const float4 xv = *(const float4*)(gx + d);
            float4 o;
            o.x = xv.x + yv[0]; o.y = xv.y + yv[1];
            o.z = xv.z + yv[2]; o.w = xv.w + yv[3];
            *(float4*)(go + d) = o;
        }
        __syncthreads();
    }
}

extern "C" void kernel_launch(void* const* d_in, const int* in_sizes, int n_in,
                              void* d_out, int out_size, void* d_ws, size_t ws_size,
                              hipStream_t stream) {
    (void)in_sizes; (void)n_in; (void)out_size; (void)ws_size;
    const float* X    = (const float*)d_in[0];
    const float* ln_w = (const float*)d_in[1];
    const float* ln_b = (const float*)d_in[2];
    const float* Wi   = (const float*)d_in[3];
    const float* b_in = (const float*)d_in[4];
    const float* Wc   = (const float*)d_in[5];
    const float* cb   = (const float*)d_in[6];
    float* OUT = (float*)d_out;
    ushort_t* X1 = (ushort_t*)d_ws;   // 100352*192 bf16 = 38.5 MB

    k0_wt<<<(9 * 96 * 192 + 255) / 256, 256, 0, stream>>>(Wc, Wi);
    k1_ln_proj<<<NPIX / 64, 256, 0, stream>>>(X, ln_w, ln_b, b_in, X1);
    k2_conv_mfma<<<K2_NWG, 256, 0, stream>>>(X1, cb, X, OUT);
}

// Round 11
// 146.267 us; speedup vs baseline: 1.3473x; 1.3473x over previous
//
#include <hip/hip_runtime.h>
#include <hip/hip_bf16.h>

#define D_MODEL 96
#define D_INNER 192
#define BATCH 32
#define HH 56
#define WW 56
#define NPIX (BATCH*HH*WW)   // 100352
#define LN_EPS 1e-5f
#define TAPS 18432           // shorts per tap slab (96 oc * 192 ic)
#define TAPBYTES 36864
#define K2_NWG 392           // NPIX / 256 = 8 * 49 (bijective XCD swizzle)
#define K2_CPX 49            // blocks per XCD chunk = exactly 4 images

typedef unsigned short ushort_t;
typedef __attribute__((ext_vector_type(8))) short short8;   // 8 bf16 (4 VGPRs)
typedef __attribute__((ext_vector_type(4))) float f32x4;

// conv weights transposed to [tap][oc][ic] bf16 (331 KB) and
// in_proj live-half transposed to [oc=192][ic=96] bf16 (36.9 KB), module .data.
__device__ __align__(16) ushort_t g_Wt[9 * 96 * 192];
__device__ __align__(16) ushort_t g_Wit[192 * 96];

// round-to-nearest-even f32 -> bf16
static __device__ __forceinline__ unsigned short f2bf(float f) {
    unsigned u = __float_as_uint(f);
    unsigned r = (u + 0x7fffu + ((u >> 16) & 1u)) >> 16;
    return (unsigned short)r;
}

// ---------------------------------------------------------------------------
// Kernel 0: weight prep. (unchanged, verified)
// ---------------------------------------------------------------------------
__global__ __launch_bounds__(256) void k0_wt(const float* __restrict__ Wc,
                                             const float* __restrict__ Wi) {
    const int o = blockIdx.x * 256 + threadIdx.x;
    if (o < 9 * 96 * 192) {
        const int tap = o / (96 * 192);
        const int rem = o - tap * 96 * 192;
        const int oc = rem / 192;
        const int ic = rem - oc * 192;
        g_Wt[o] = f2bf(Wc[(tap * 192 + ic) * 96 + oc]);
    }
    if (o < 192 * 96) {
        const int oc = o / 96, ic = o - oc * 96;
        g_Wit[o] = f2bf(Wi[ic * 384 + oc]);
    }
}

// ---------------------------------------------------------------------------
// Kernel 1: LayerNorm + in_projection (96 -> live 192) via bf16 MFMA.
// (byte-identical to round 9, verified passing)
// ---------------------------------------------------------------------------
__global__ __launch_bounds__(256) void k1_ln_proj(
    const float* __restrict__ X, const float* __restrict__ ln_w,
    const float* __restrict__ ln_b, const float* __restrict__ b_in,
    ushort_t* __restrict__ X1)
{
    __shared__ ushort_t sH[64 * 104];    // 13,312 B (GEMM B-operand)
    __shared__ ushort_t sO[64 * 200];    // 25,600 B (output transpose)
    const int t = threadIdx.x;

    const int g = t >> 2, tig = t & 3;
    const int pix = blockIdx.x * 64 + g;
    const float* xp = X + (size_t)pix * 96 + tig * 24;
    float4 xq[6];
    float s = 0.f;
    #pragma unroll
    for (int c = 0; c < 6; ++c) {
        xq[c] = *(const float4*)(xp + c * 4);
        s += xq[c].x + xq[c].y + xq[c].z + xq[c].w;
    }
    s += __shfl_xor(s, 1, 4);
    s += __shfl_xor(s, 2, 4);
    const float mu = s * (1.f / 96.f);
    float v = 0.f;
    #pragma unroll
    for (int c = 0; c < 6; ++c) {
        const float d0 = xq[c].x - mu, d1 = xq[c].y - mu;
        const float d2 = xq[c].z - mu, d3 = xq[c].w - mu;
        v += d0 * d0 + d1 * d1 + d2 * d2 + d3 * d3;
    }
    v += __shfl_xor(v, 1, 4);
    v += __shfl_xor(v, 2, 4);
    const float rs = rsqrtf(v * (1.f / 96.f) + LN_EPS);
    #pragma unroll
    for (int c = 0; c < 6; ++c) {
        const float4 lw = *(const float4*)(ln_w + tig * 24 + c * 4);
        const float4 lb = *(const float4*)(ln_b + tig * 24 + c * 4);
        const unsigned p0 = (unsigned)f2bf((xq[c].x - mu) * rs * lw.x + lb.x)
                          | ((unsigned)f2bf((xq[c].y - mu) * rs * lw.y + lb.y) << 16);
        const unsigned p1 = (unsigned)f2bf((xq[c].z - mu) * rs * lw.z + lb.z)
                          | ((unsigned)f2bf((xq[c].w - mu) * rs * lw.w + lb.w) << 16);
        uint2 u; u.x = p0; u.y = p1;
        *(uint2*)&sH[g * 104 + tig * 24 + c * 4] = u;
    }
    __syncthreads();

    const int w = t >> 6, l = t & 63;
    const int lm = l & 15, lq = l >> 4;
    const ushort_t* hp = &sH[(w * 16 + lm) * 104 + lq * 8];

    f32x4 acc[12];
    const f32x4 zf = {0.f, 0.f, 0.f, 0.f};
    #pragma unroll
    for (int mt = 0; mt < 12; ++mt) acc[mt] = zf;

    #pragma unroll
    for (int kk = 0; kk < 3; ++kk) {
        const short8 hb = *(const short8*)(hp + kk * 32);
        #pragma unroll
        for (int mt = 0; mt < 12; ++mt) {
            const short8 wa = *(const short8*)(g_Wit + (mt * 16 + lm) * 96 + kk * 32 + lq * 8);
            acc[mt] = __builtin_amdgcn_mfma_f32_16x16x32_bf16(wa, hb, acc[mt], 0, 0, 0);
        }
    }

    #pragma unroll
    for (int mt = 0; mt < 12; ++mt) {
        const int oc0 = mt * 16 + lq * 4;
        const float4 bv = *(const float4*)(b_in + oc0);
        uint2 u;
        u.x = (unsigned)f2bf(acc[mt][0] + bv.x) | ((unsigned)f2bf(acc[mt][1] + bv.y) << 16);
        u.y = (unsigned)f2bf(acc[mt][2] + bv.z) | ((unsigned)f2bf(acc[mt][3] + bv.w) << 16);
        *(uint2*)&sO[(w * 16 + lm) * 200 + oc0] = u;
    }
    __syncthreads();

    const char* sOb = (const char*)sO + w * 16 * 400;
    char* gdst = (char*)X1 + (size_t)(blockIdx.x * 64 + w * 16) * 384;
    #pragma unroll
    for (int c = 0; c < 6; ++c) {
        const int gb = c * 1024 + l * 16;
        const int px = gb / 384, b = gb - px * 384;
        const uint4 val = *(const uint4*)(sOb + px * 400 + b);
        *(uint4*)(gdst + gb) = val;
    }
}

// ---------------------------------------------------------------------------
// Kernel 2: 3x3 conv (192 -> 96) MFMA + bias + SiLU + residual.
// Byte-identical to round 9 (verified: 112 us, the best k2) EXCEPT one
// change: T1 bijective XCD swizzle of the block id. 392 = 8 * 49; 49 blocks
// = exactly 4 images, so each XCD's L2 holds a ~1.2 MB active X1 window ->
// the 9x halo re-reads become L2 hits instead of L3 round-trips.
// ---------------------------------------------------------------------------
__global__ __launch_bounds__(256, 2) void k2_conv_mfma(
    const ushort_t* __restrict__ X1, const float* __restrict__ conv_b,
    const float* __restrict__ X, float* __restrict__ OUT)
{
    __shared__ ushort_t sW[2][TAPS];   // 73,728 B -> 2 blocks/CU
    const int t = threadIdx.x;
    const int w = t >> 6, l = t & 63;
    const int lm = l & 15, lq = l >> 4;

    // T1: XCD (bid&7) owns logical blocks [(bid&7)*49, +49) = 4 images.
    const int lb = ((int)blockIdx.x & 7) * K2_CPX + ((int)blockIdx.x >> 3);

    const int P0 = lb * 256 + w * 64;
    const int img = P0 / 3136;
    const int ploc0 = P0 - img * 3136;
    int rr[4], cc[4];
    #pragma unroll
    for (int i = 0; i < 4; ++i) {
        const int pl = ploc0 + i * 16 + lm;
        rr[i] = pl / 56;
        cc[i] = pl - rr[i] * 56;
    }
    const size_t imgbase = (size_t)img * 3136 * 192;

    const int sbase = w * 9216 + l * 16;

    f32x4 acc[4][6];
    const f32x4 zf = {0.f, 0.f, 0.f, 0.f};
    #pragma unroll
    for (int i = 0; i < 4; ++i)
        #pragma unroll
        for (int n = 0; n < 6; ++n) acc[i][n] = zf;

    const short8 zero8 = {0, 0, 0, 0, 0, 0, 0, 0};
    const int bkey = (lm & 7) << 4;
    const int bbase0 = lm * 384 + lq * 16;

    // ---- prologue: stage tap 0 into buf 0 ----
    uint4 r[9];
    #pragma unroll
    for (int j = 0; j < 9; ++j)
        r[j] = *(const uint4*)((const char*)g_Wt + sbase + j * 1024);
    #pragma unroll
    for (int j = 0; j < 9; ++j) {
        const int D = sbase + j * 1024;
        *(uint4*)((char*)&sW[0][0] + (D ^ (((D / 384) & 7) << 4))) = r[j];
    }
    __syncthreads();

    #pragma unroll 1
    for (int tap = 0; tap < 9; ++tap) {
        if (tap < 8) {
            const char* gsrc = (const char*)g_Wt + (size_t)(tap + 1) * TAPBYTES;
            #pragma unroll
            for (int j = 0; j < 9; ++j)
                r[j] = *(const uint4*)(gsrc + sbase + j * 1024);
        }

        const int ky = tap / 3, kx = tap - (tap / 3) * 3;
        const ushort_t* abase[4];
        bool av[4];
        #pragma unroll
        for (int i = 0; i < 4; ++i) {
            const int gr = rr[i] + ky - 1, gc = cc[i] + kx - 1;
            av[i] = (gr >= 0) && (gr < HH) && (gc >= 0) && (gc < WW);
            abase[i] = X1 + imgbase + (size_t)(gr * WW + gc) * 192 + lq * 8;
        }
        const char* bufp = (const char*)&sW[tap & 1][0];

        #pragma unroll
        for (int kk = 0; kk < 6; ++kk) {
            short8 b[6];
            #pragma unroll
            for (int n = 0; n < 6; ++n) {
                const int A = bbase0 + n * 6144 + kk * 64;
                b[n] = *(const short8*)(bufp + (A ^ bkey));
            }
            short8 a[4];
            #pragma unroll
            for (int i = 0; i < 4; ++i)
                a[i] = av[i] ? *(const short8*)(abase[i] + kk * 32) : zero8;
            #pragma unroll
            for (int i = 0; i < 4; ++i)
                #pragma unroll
                for (int n = 0; n < 6; ++n)
                    acc[i][n] = __builtin_amdgcn_mfma_f32_16x16x32_bf16(
                        a[i], b[n], acc[i][n], 0, 0, 0);
        }

        if (tap < 8) {
            char* dst = (char*)&sW[(tap + 1) & 1][0];
            #pragma unroll
            for (int j = 0; j < 9; ++j) {
                const int D = sbase + j * 1024;
                *(uint4*)(dst + (D ^ (((D / 384) & 7) << 4))) = r[j];
            }
        }
        __syncthreads();
    }

    // ---- coalesced epilogue through LDS (sW now dead) ----
    float* sY = (float*)&sW[0][0] + w * 1600;
    float bvn[6];
    #pragma unroll
    for (int n = 0; n < 6; ++n) bvn[n] = conv_b[n * 16 + lm];

    #pragma unroll
    for (int i = 0; i < 4; ++i) {           // fully unrolled: acc stays in VGPRs
        #pragma unroll
        for (int n = 0; n < 6; ++n) {
            #pragma unroll
            for (int r4 = 0; r4 < 4; ++r4) {
                const float y = acc[i][n][r4] + bvn[n];
                const float sig = 1.f / (1.f + __expf(-y));
                sY[(lq * 4 + r4) * 100 + n * 16 + lm] = y * sig;
            }
        }
        __syncthreads();
        const float* gx = X + (size_t)(P0 + i * 16) * 96;
        float* go = OUT + (size_t)(P0 + i * 16) * 96;
        #pragma unroll
        for (int c = 0; c < 6; ++c) {
            const int d = c * 256 + l * 4;           // dword index in span
            const int px = d / 96, b = d - px * 96;
            const f32x4 yv = *(const f32x4*)(sY + px * 100 + b);
            const float4 xv = *(const float4*)(gx + d);
            float4 o;
            o.x = xv.x + yv[0]; o.y = xv.y + yv[1];
            o.z = xv.z + yv[2]; o.w = xv.w + yv[3];
            *(float4*)(go + d) = o;
        }
        __syncthreads();
    }
}

extern "C" void kernel_launch(void* const* d_in, const int* in_sizes, int n_in,
                              void* d_out, int out_size, void* d_ws, size_t ws_size,
                              hipStream_t stream) {
    (void)in_sizes; (void)n_in; (void)out_size; (void)ws_size;
    const float* X    = (const float*)d_in[0];
    const float* ln_w = (const float*)d_in[1];
    const float* ln_b = (const float*)d_in[2];
    const float* Wi   = (const float*)d_in[3];
    const float* b_in = (const float*)d_in[4];
    const float* Wc   = (const float*)d_in[5];
    const float* cb   = (const float*)d_in[6];
    float* OUT = (float*)d_out;
    ushort_t* X1 = (ushort_t*)d_ws;   // 100352*192 bf16 = 38.5 MB

    k0_wt<<<(9 * 96 * 192 + 255) / 256, 256, 0, stream>>>(Wc, Wi);
    k1_ln_proj<<<NPIX / 64, 256, 0, stream>>>(X, ln_w, ln_b, b_in, X1);
    k2_conv_mfma<<<K2_NWG, 256, 0, stream>>>(X1, cb, X, OUT);
}